// Round 4
// baseline (751.008 us; speedup 1.0000x reference)
//
#include <hip/hip_runtime.h>

// out[b, r, c] = (c >= r) ? in[b, triu_index(r, c)] : 0
// triu_index(r,c) = r*M - r*(r-1)/2 + (c - r)   (np.triu_indices row-major order)
//
// Persistent grid-stride kernel, PLAIN cached stores (round-1 retry minus the
// nontemporal stores — single-variable experiment). Grid-stride step =
// 2048 blocks * 256 threads = 524,288 quads = exactly TWO (M x M) matrices,
// so each thread's (row, quad) position — and its triangle classification —
// is loop-invariant. The branch hoists out of the loop, leaving three
// specialized streaming loops; unroll x8 gives up to 8 loads + 8 stores in
// flight per wave. Instantaneous write window = 8 MiB contiguous (fill-shaped).

constexpr int M = 1024;
constexpr int BATCH = 128;
constexpr int TRIU_LEN = M * (M + 1) / 2;       // 524800
constexpr int QPR = M / 4;                      // 256 quads per row
constexpr int TOTAL_QUADS = BATCH * M * QPR;    // 33,554,432
constexpr int BLOCK = 256;
constexpr int GRID = 2048;
constexpr int NTHREADS = BLOCK * GRID;          // 524,288 = 2 matrices of quads
constexpr int ITERS = TOTAL_QUADS / NTHREADS;   // 64 (batch advances by 2/iter)

static_assert(NTHREADS == 2 * M * QPR, "stride must be exactly 2 matrices");
static_assert(TOTAL_QUADS % NTHREADS == 0, "exact tiling");

typedef float v4f __attribute__((ext_vector_type(4)));

__global__ __launch_bounds__(BLOCK) void triu_scatter_kernel(
    const float* __restrict__ in, float* __restrict__ out) {
    const int tid = blockIdx.x * BLOCK + threadIdx.x;   // 0 .. 524287
    const int qc = tid & (QPR - 1);                     // quad within row
    const int r  = (tid >> 8) & (M - 1);                // row (loop-invariant)
    const int b0 = tid >> 18;                           // starting batch: 0 or 1
    const int c0 = qc << 2;

    // p[c] = in[b, triu_index(r, c)], valid for c in [r, M-1]
    const int row_base = r * (M - 1) - ((r * (r - 1)) >> 1);
    const float* p = in + b0 * TRIU_LEN + row_base;
    v4f* o = reinterpret_cast<v4f*>(out) + tid;

    if (c0 >= r) {
        // whole quad in upper triangle — pure streaming copy
#pragma unroll 8
        for (int k = 0; k < ITERS; ++k) {
            v4f v;
            v.x = p[c0];
            v.y = p[c0 + 1];
            v.z = p[c0 + 2];
            v.w = p[c0 + 3];
            *o = v;
            p += 2 * TRIU_LEN;
            o += NTHREADS;
        }
    } else if (c0 + 3 < r) {
        // whole quad strictly below diagonal — store-only, fill-kernel shape
        const v4f z = {0.f, 0.f, 0.f, 0.f};
#pragma unroll 8
        for (int k = 0; k < ITERS; ++k) {
            *o = z;
            o += NTHREADS;
        }
    } else {
        // boundary quad: c0 < r <= c0+3 (at most one per row).
        // Clamped addresses keep loads unconditional so they pipeline.
        const int c1 = c0 + 1, c2 = c0 + 2, c3 = c0 + 3;
        const bool m1 = (c1 >= r), m2 = (c2 >= r);
        const int a1 = m1 ? c1 : c3;
        const int a2 = m2 ? c2 : c3;
#pragma unroll 4
        for (int k = 0; k < ITERS; ++k) {
            v4f v;
            const float ly = p[a1];
            const float lz = p[a2];
            const float lw = p[c3];                      // c3 >= r always here
            v.x = 0.f;
            v.y = m1 ? ly : 0.f;
            v.z = m2 ? lz : 0.f;
            v.w = lw;
            *o = v;
            p += 2 * TRIU_LEN;
            o += NTHREADS;
        }
    }
}

extern "C" void kernel_launch(void* const* d_in, const int* in_sizes, int n_in,
                              void* d_out, int out_size, void* d_ws, size_t ws_size,
                              hipStream_t stream) {
    const float* in = (const float*)d_in[0];
    float* out = (float*)d_out;
    triu_scatter_kernel<<<GRID, BLOCK, 0, stream>>>(in, out);
}

// Round 6
// 666.463 us; speedup vs baseline: 1.1269x; 1.1269x over previous
//
#include <hip/hip_runtime.h>

// out[b, r, c] = (c >= r) ? in[b, triu_index(r, c)] : 0
// triu_index(r,c) = r*M - r*(r-1)/2 + (c - r)   (np.triu_indices row-major order)
//
// Round-0 one-shot in-order sweep (best so far), with ONE change: the
// upper-triangle load is a single unaligned 16 B vector load instead of four
// 4 B loads at 16 B lane-stride. The strided-dword form makes each load
// instruction touch the wave's whole 1 KiB span at 1/4 density (~4x the L1/TA
// sector requests); the dwordx4 form is one dense contiguous access. CDNA
// supports global_load_dwordx4 at dword alignment (unaligned access mode).

constexpr int M = 1024;
constexpr int BATCH = 128;
constexpr int TRIU_LEN = M * (M + 1) / 2;  // 524800
constexpr int QUADS_PER_ROW = M / 4;       // 256

typedef float v4f __attribute__((ext_vector_type(4)));
typedef float v4u __attribute__((ext_vector_type(4), aligned(4)));  // 4B-aligned

__global__ __launch_bounds__(256) void triu_scatter_kernel(
    const float* __restrict__ in, float* __restrict__ out) {
    // One thread per 4 consecutive output columns (one dwordx4 store).
    int tid = blockIdx.x * blockDim.x + threadIdx.x;  // 0 .. B*M*256-1
    int qc = tid & (QUADS_PER_ROW - 1);   // quad within row
    int r  = (tid >> 8) & (M - 1);        // row
    int b  = tid >> 18;                   // batch
    int c0 = qc << 2;

    // p[c] = in[b, triu_index(r, c)], valid for c in [r, M-1]
    int row_base = r * M - (r * (r - 1)) / 2 - r;
    const float* inb = in + (long)b * TRIU_LEN + row_base;

    v4f v;
    if (c0 >= r) {
        // whole quad in upper triangle — single unaligned 16 B vector load
        v = *reinterpret_cast<const v4u*>(inb + c0);
    } else if (c0 + 3 < r) {
        // whole quad strictly below diagonal
        v = (v4f){0.f, 0.f, 0.f, 0.f};
    } else {
        // boundary quad (exactly one per row) — clamped unconditional loads
        const int c1 = c0 + 1, c2 = c0 + 2, c3 = c0 + 3;
        const bool m1 = (c1 >= r), m2 = (c2 >= r);
        const float ly = inb[m1 ? c1 : c3];
        const float lz = inb[m2 ? c2 : c3];
        const float lw = inb[c3];          // c3 >= r always here
        v.x = 0.f;
        v.y = m1 ? ly : 0.f;
        v.z = m2 ? lz : 0.f;
        v.w = lw;
    }

    reinterpret_cast<v4f*>(out)[tid] = v;
}

extern "C" void kernel_launch(void* const* d_in, const int* in_sizes, int n_in,
                              void* d_out, int out_size, void* d_ws, size_t ws_size,
                              hipStream_t stream) {
    const float* in = (const float*)d_in[0];
    float* out = (float*)d_out;

    const int total_quads = BATCH * M * QUADS_PER_ROW;  // 33,554,432
    const int block = 256;
    const int grid = total_quads / block;               // 131072

    triu_scatter_kernel<<<grid, block, 0, stream>>>(in, out);
}